// Round 6
// baseline (12624.634 us; speedup 1.0000x reference)
//
#include <hip/hip_runtime.h>
#include <hip/hip_bf16.h>

// Stacked 2-layer Elman RNN, B=2048 T=256 H=512 OUT=1.
//
// Round-5 lesson (m69-consistent): per-CU register file is only 512KB
// (per-SIMD pool = 512 wave-regs; waves/CU halves at vgpr {64,128,256}).
// Weights (1.5MB fp16) CANNOT be register/LDS-stationary on one CU.
// Correct regime: L2-resident weight STREAMING, latency-hidden.
//   - 128 blocks x 512 threads (8 waves, 2/SIMD -> 256-reg budget, no spill)
//   - wave w owns n-tiles 4w..4w+3 for ALL THREE matmuls; layer-1 partials
//     stay in registers (no pacc LDS round-trip); 2 barriers/step
//   - B-fragments streamed with distance-2 rolling prefetch (3 buffers,
//     static %3 indices); phase-B / next-step prologues issued before the
//     tanh epilogue + barrier so loads stay in flight across the barrier
//   - 34KB dead LDS pad forces 1 block/CU (2 blocks would share the
//     per-CU L1/L2 fabric and halve effective stream BW)
// Floor: 128 CUs x 1.5MB x 256 steps = 49GB / 34.5TB/s L2 ~= 1.4ms.

typedef _Float16 half8 __attribute__((ext_vector_type(8)));
typedef float f32x4 __attribute__((ext_vector_type(4)));

#define T_STEPS 256
#define H_DIM   512
#define BM      16

__device__ __forceinline__ float tanh_fast(float z){
  float az = fabsf(z);
  float e  = __expf(-2.0f * az);
  float r  = (1.0f - e) * __builtin_amdgcn_rcpf(1.0f + e);
  return copysignf(r, z);
}

// fp32 [k][n] -> fp16 MFMA-B fragments: out[(nt*16+kc)*64+lane] = 8 halves,
// col = nt*16 + (lane&15), k = kc*32 + (lane>>4)*8 + j
__global__ void prep_w_45028437131357(const float* __restrict__ W,
                                      half8* __restrict__ out){
  int tid  = blockIdx.x * 256 + threadIdx.x;
  int lane = tid & 63;
  int kc   = (tid >> 6) & 15;
  int nt   = tid >> 10;
  int col  = nt * 16 + (lane & 15);
  int k0   = kc * 32 + (lane >> 4) * 8;
  half8 v;
#pragma unroll
  for (int j = 0; j < 8; ++j) v[j] = (_Float16)W[(k0 + j) * H_DIM + col];
  out[tid] = v;
}

// LDS h layout: element (row, c) at byte  row*1024 + ((c*2) ^ ((row&7)<<4))

__global__ __launch_bounds__(512, 2)
void rnn_main_45028437131357(const float* __restrict__ x,
                             const float* __restrict__ Wx0,
                             const float* __restrict__ bx0,
                             const float* __restrict__ bh0,
                             const float* __restrict__ bx1,
                             const float* __restrict__ bh1,
                             const float* __restrict__ Wfc,
                             const float* __restrict__ bfc,
                             const half8* __restrict__ Wh0f,
                             const half8* __restrict__ Wx1f,
                             const half8* __restrict__ Wh1f,
                             float* __restrict__ out){
  __shared__ __align__(16) char h0raw[2][BM * 1024];
  __shared__ __align__(16) char h1raw[BM * 1024];
  __shared__ float xl[BM];
  __shared__ char lds_pad[34 * 1024];   // force 1 block/CU (total > 80KB)

  const int tid  = threadIdx.x;
  const int lane = tid & 63;
  const int w    = tid >> 6;            // 0..7, owns n-tiles 4w..4w+3
  const int r0   = blockIdx.x * BM;

  if (out == nullptr) ((volatile char*)lds_pad)[0] = 1;  // keep pad alive

  // zero initial hidden state
  for (int i = tid; i < 2 * BM * 256; i += 512) ((float*)h0raw)[i] = 0.0f;
  for (int i = tid; i < BM * 256;     i += 512) ((float*)h1raw)[i] = 0.0f;

  // weight fragment pointers: frag(i,kc) at p[(i*16+kc)*64]
  const half8* pA0 = Wh0f + (4 * w) * 16 * 64 + lane;
  const half8* pA1 = Wh1f + (4 * w) * 16 * 64 + lane;
  const half8* pX  = Wx1f + (4 * w) * 16 * 64 + lane;

  const int cl      = lane & 15;
  const int kg      = lane >> 4;
  const int aBase   = cl * 1024 + kg * 16;   // + kc*64, then ^aSwz
  const int aSwz    = (cl & 7) << 4;
  const int rowBase = kg * 4;

  // per-column constants for the 4 owned n-tiles
  float wx0c[4], b0c[4], b1c[4];
  int   colA[4];
#pragma unroll
  for (int i = 0; i < 4; ++i){
    int col = (4 * w + i) * 16 + cl;
    colA[i] = col;
    wx0c[i] = Wx0[col];
    b0c[i]  = bx0[col] + bh0[col];
    b1c[i]  = bx1[col] + bh1[col];
  }

  float xreg = 0.0f;
  if (tid < BM) xreg = x[(r0 + tid) * T_STEPS];

  const f32x4 z4 = {0.f, 0.f, 0.f, 0.f};
  int s = 0;

  // phase-A prologue: kc = 0,1 fragment groups (weights identical每step)
  half8 w0buf[3][4], w1buf[3][4];
#pragma unroll
  for (int p = 0; p < 2; ++p)
#pragma unroll
    for (int i = 0; i < 4; ++i){
      w0buf[p][i] = pA0[(i * 16 + p) * 64];
      w1buf[p][i] = pA1[(i * 16 + p) * 64];
    }

  for (int t = 0; t < T_STEPS; ++t){
    if (tid < BM) xl[tid] = xreg;
    __syncthreads();                      // B0: h1_new(t-1) + xl visible
    {
      int tn = (t + 1 < T_STEPS) ? t + 1 : t;
      if (tid < BM) xreg = x[(r0 + tid) * T_STEPS + tn];
    }

    // ---- phase A: acc0 = h0_old@Wh0 ; acc1 = h1_old@Wh1 (in regs) ----
    f32x4 acc0[4] = {z4, z4, z4, z4};
    f32x4 acc1[4] = {z4, z4, z4, z4};
#pragma unroll
    for (int kc = 0; kc < 16; ++kc){
      const int cur = kc % 3;
      const int nxt = (kc + 2) % 3;
      if (kc < 14){
#pragma unroll
        for (int i = 0; i < 4; ++i){
          w0buf[nxt][i] = pA0[(i * 16 + kc + 2) * 64];
          w1buf[nxt][i] = pA1[(i * 16 + kc + 2) * 64];
        }
      }
      half8 a0 = *(const half8*)(h0raw[s] + ((aBase + kc * 64) ^ aSwz));
      half8 a1 = *(const half8*)(h1raw    + ((aBase + kc * 64) ^ aSwz));
#pragma unroll
      for (int i = 0; i < 4; ++i)
        acc0[i] = __builtin_amdgcn_mfma_f32_16x16x32_f16(a0, w0buf[cur][i], acc0[i], 0, 0, 0);
#pragma unroll
      for (int i = 0; i < 4; ++i)
        acc1[i] = __builtin_amdgcn_mfma_f32_16x16x32_f16(a1, w1buf[cur][i], acc1[i], 0, 0, 0);
    }

    // phase-B prologue loads: in flight across the epilogue + barrier
    half8 wxbuf[3][4];
#pragma unroll
    for (int p = 0; p < 2; ++p)
#pragma unroll
      for (int i = 0; i < 4; ++i)
        wxbuf[p][i] = pX[(i * 16 + p) * 64];

    // h0 epilogue: tanh(acc0 + b0 + x*wx0) -> h0raw[s^1]
    {
      float xv[4];
#pragma unroll
      for (int rg = 0; rg < 4; ++rg) xv[rg] = xl[rowBase + rg];
#pragma unroll
      for (int i = 0; i < 4; ++i)
#pragma unroll
        for (int rg = 0; rg < 4; ++rg){
          float z = acc0[i][rg] + b0c[i] + xv[rg] * wx0c[i];
          int row = rowBase + rg;
          *(_Float16*)(h0raw[s ^ 1] + row * 1024 +
                       ((colA[i] * 2) ^ ((row & 7) << 4))) = (_Float16)tanh_fast(z);
        }
    }
    __syncthreads();                      // B1: h0_new visible

    // ---- phase B: acc1 += h0_new@Wx1 ----
#pragma unroll
    for (int kc = 0; kc < 16; ++kc){
      const int cur = kc % 3;
      const int nxt = (kc + 2) % 3;
      if (kc < 14){
#pragma unroll
        for (int i = 0; i < 4; ++i)
          wxbuf[nxt][i] = pX[(i * 16 + kc + 2) * 64];
      }
      half8 a = *(const half8*)(h0raw[s ^ 1] + ((aBase + kc * 64) ^ aSwz));
#pragma unroll
      for (int i = 0; i < 4; ++i)
        acc1[i] = __builtin_amdgcn_mfma_f32_16x16x32_f16(a, wxbuf[cur][i], acc1[i], 0, 0, 0);
    }

    // next-step phase-A prologue (same addresses every step): issue early
#pragma unroll
    for (int p = 0; p < 2; ++p)
#pragma unroll
      for (int i = 0; i < 4; ++i){
        w0buf[p][i] = pA0[(i * 16 + p) * 64];
        w1buf[p][i] = pA1[(i * 16 + p) * 64];
      }

    // h1 epilogue: tanh(acc1 + b1) -> h1raw (visible after next B0)
#pragma unroll
    for (int i = 0; i < 4; ++i)
#pragma unroll
      for (int rg = 0; rg < 4; ++rg){
        float z = acc1[i][rg] + b1c[i];
        int row = rowBase + rg;
        *(_Float16*)(h1raw + row * 1024 +
                     ((colA[i] * 2) ^ ((row & 7) << 4))) = (_Float16)tanh_fast(z);
      }
    s ^= 1;
  }
  __syncthreads();

  // ---- final FC: out[r] = h1[r,:] . Wfc + bfc ----
  {
    int r  = tid >> 5;        // 0..15
    int g2 = tid & 31;
    float p = 0.0f;
#pragma unroll
    for (int k2 = 0; k2 < 16; ++k2){
      int c = g2 + 32 * k2;
      float hv = (float)*(const _Float16*)(h1raw + r * 1024 +
                                           ((c * 2) ^ ((r & 7) << 4)));
      p += hv * Wfc[c];
    }
#pragma unroll
    for (int off = 16; off >= 1; off >>= 1) p += __shfl_xor(p, off);
    if (g2 == 0) out[r0 + r] = p + bfc[0];
  }
}

extern "C" void kernel_launch(void* const* d_in, const int* in_sizes, int n_in,
                              void* d_out, int out_size, void* d_ws, size_t ws_size,
                              hipStream_t stream) {
  const float* x   = (const float*)d_in[0];
  const float* Wx0 = (const float*)d_in[1];
  const float* bx0 = (const float*)d_in[2];
  const float* Wh0 = (const float*)d_in[3];
  const float* bh0 = (const float*)d_in[4];
  const float* Wx1 = (const float*)d_in[5];
  const float* bx1 = (const float*)d_in[6];
  const float* Wh1 = (const float*)d_in[7];
  const float* bh1 = (const float*)d_in[8];
  const float* Wfc = (const float*)d_in[9];
  const float* bfc = (const float*)d_in[10];

  _Float16* wsH = (_Float16*)d_ws;
  half8* Wh0f = (half8*)(wsH);
  half8* Wx1f = (half8*)(wsH + 262144);
  half8* Wh1f = (half8*)(wsH + 524288);

  prep_w_45028437131357<<<128, 256, 0, stream>>>(Wh0, Wh0f);
  prep_w_45028437131357<<<128, 256, 0, stream>>>(Wx1, Wx1f);
  prep_w_45028437131357<<<128, 256, 0, stream>>>(Wh1, Wh1f);

  rnn_main_45028437131357<<<128, 512, 0, stream>>>(
      x, Wx0, bx0, bh0, bx1, bh1, Wfc, bfc,
      (const half8*)Wh0f, (const half8*)Wx1f, (const half8*)Wh1f,
      (float*)d_out);
}